// Round 2
// baseline (515.151 us; speedup 1.0000x reference)
//
#include <hip/hip_runtime.h>
#include <hip/hip_bf16.h>

// Problem constants (BoundaryPredictor2): B=8, L=1500, D=1024, H=8, HD=128, S=300
// All float tensors are float32 (per reference); we convert to bf16 internally
// for MFMA GEMMs and write fp32 output.
#define BPK_B 8
#define BPK_L 1500
#define BPK_D 1024
#define BPK_H 8
#define BPK_HD 128
#define BPK_S 300
#define BPK_EPS 1e-5f
#define BPK_M (BPK_B * BPK_L)      // 12000 token rows
#define BPK_MPAD 12032             // 94 * 128
#define BPK_MS (BPK_B * BPK_S)     // 2400 pooled rows
#define BPK_MSPAD 2432             // 19 * 128

typedef __hip_bfloat16 bf16;
typedef __bf16 bf16x8 __attribute__((ext_vector_type(8)));
typedef float v4f __attribute__((ext_vector_type(4)));

static __device__ __forceinline__ float bf_lo(unsigned u) {
    return __uint_as_float((u & 0xffffu) << 16);
}
static __device__ __forceinline__ float bf_hi(unsigned u) {
    return __uint_as_float((u >> 16) << 16);
}
static __device__ __forceinline__ void bpk_store(float v, float* p) { *p = v; }
static __device__ __forceinline__ void bpk_store(float v, bf16* p) { *p = __float2bfloat16(v); }

// ---------------------------------------------------------------------------
// Kernel 0: fp32 -> bf16 conversion (for the 1024x1024 weight matrices).
// ---------------------------------------------------------------------------
__global__ __launch_bounds__(256) void bpk_conv_kernel(const float* __restrict__ src,
                                                       bf16* __restrict__ dst) {
    int i = (blockIdx.x * 256 + threadIdx.x) * 4;
    float4 v = *(const float4*)(src + i);
    bf16* d = dst + i;
    d[0] = __float2bfloat16(v.x);
    d[1] = __float2bfloat16(v.y);
    d[2] = __float2bfloat16(v.z);
    d[3] = __float2bfloat16(v.w);
}

// ---------------------------------------------------------------------------
// Kernel 1: per-batch segment scan. seg_id is non-decreasing, so each segment
// is a contiguous token range [start, start+cnt). Serial loop per batch.
// ---------------------------------------------------------------------------
__global__ void bpk_seg_kernel(const float* __restrict__ boundaries,
                               const float* __restrict__ lengths,
                               int* __restrict__ seg_start,
                               int* __restrict__ seg_cnt) {
    int b = blockIdx.x;
    if (threadIdx.x != 0) return;
    int alen = (int)(lengths[b] * (float)BPK_L);  // trunc, matches .astype(int32)
    int* st = seg_start + b * BPK_S;
    int* cn = seg_cnt + b * BPK_S;
    for (int s = 0; s < BPK_S; s++) { st[s] = 0; cn[s] = 0; }
    int cum = 0;
    const float* bd = boundaries + b * BPK_L;
    for (int t = 0; t < BPK_L; t++) {
        int sid = cum;                 // seg_id = #boundaries strictly before t
        if (bd[t] >= 0.5f) cum++;
        if (t < alen && sid < BPK_S) {
            if (cn[sid] == 0) st[sid] = t;
            cn[sid]++;
        }
    }
}

// ---------------------------------------------------------------------------
// Kernel 2: LayerNorm (biased variance), fp32 in -> bf16 out. 1 block/row.
// ---------------------------------------------------------------------------
__global__ __launch_bounds__(256) void bpk_ln_kernel(const float* __restrict__ x,
                                                     const float* __restrict__ gamma,
                                                     const float* __restrict__ beta,
                                                     bf16* __restrict__ y) {
    int row = blockIdx.x;
    int tid = threadIdx.x;
    const float* xr = x + (size_t)row * BPK_D;
    float4 f = *(const float4*)(xr + tid * 4);
    float s = f.x + f.y + f.z + f.w;
    float sq = f.x * f.x + f.y * f.y + f.z * f.z + f.w * f.w;
    #pragma unroll
    for (int off = 32; off > 0; off >>= 1) {
        s += __shfl_down(s, off);
        sq += __shfl_down(sq, off);
    }
    __shared__ float ls[4], lsq[4];
    int wid = tid >> 6, lane = tid & 63;
    if (lane == 0) { ls[wid] = s; lsq[wid] = sq; }
    __syncthreads();
    s = ls[0] + ls[1] + ls[2] + ls[3];
    sq = lsq[0] + lsq[1] + lsq[2] + lsq[3];
    float mu = s * (1.0f / BPK_D);
    float var = sq * (1.0f / BPK_D) - mu * mu;
    float rs = rsqrtf(var + BPK_EPS);
    float4 g = *(const float4*)(gamma + tid * 4);
    float4 bb = *(const float4*)(beta + tid * 4);
    bf16* yr = y + (size_t)row * BPK_D + tid * 4;
    yr[0] = __float2bfloat16((f.x - mu) * rs * g.x + bb.x);
    yr[1] = __float2bfloat16((f.y - mu) * rs * g.y + bb.y);
    yr[2] = __float2bfloat16((f.z - mu) * rs * g.z + bb.z);
    yr[3] = __float2bfloat16((f.w - mu) * rs * g.w + bb.w);
}

// ---------------------------------------------------------------------------
// Kernel 3: GEMM out[m,n] = sum_k A[m,k] * W[n,k]  (A, W both K-major, bf16)
// 128x128 tile, BK=32, 4 waves, each a 64x64 subtile of 4x4 mfma 16x16x32.
// blockIdx.z picks (W0,O0)/(W1,O1). A padded to gridDim.y*128 rows; stores
// guarded by M. Output type templated (bf16 intermediates, fp32 final).
// ---------------------------------------------------------------------------
template <typename OT>
__global__ __launch_bounds__(256) void bpk_gemm_bt_kernel(
    const bf16* __restrict__ A,
    const bf16* __restrict__ W0, const bf16* __restrict__ W1,
    OT* __restrict__ O0, OT* __restrict__ O1, int M) {
    const bf16* W = blockIdx.z ? W1 : W0;
    OT* O = blockIdx.z ? O1 : O0;
    const int n0 = blockIdx.x * 128;
    const int m0 = blockIdx.y * 128;
    __shared__ bf16 As[128][32];
    __shared__ bf16 Bs[128][32];
    const int tid = threadIdx.x;
    const int lane = tid & 63, wid = tid >> 6;
    const int wm = (wid & 1) * 64, wn = (wid >> 1) * 64;
    const int lm = lane & 15, quad = lane >> 4;

    v4f acc[4][4];
    #pragma unroll
    for (int i = 0; i < 4; i++)
        #pragma unroll
        for (int j = 0; j < 4; j++)
            acc[i][j] = (v4f){0.f, 0.f, 0.f, 0.f};

    for (int k0 = 0; k0 < BPK_D; k0 += 32) {
        #pragma unroll
        for (int c = 0; c < 2; c++) {
            int id = c * 256 + tid;
            int r = id >> 2, kc = (id & 3) * 8;
            *(uint4*)&As[r][kc] = *(const uint4*)&A[(size_t)(m0 + r) * BPK_D + k0 + kc];
            *(uint4*)&Bs[r][kc] = *(const uint4*)&W[(size_t)(n0 + r) * BPK_D + k0 + kc];
        }
        __syncthreads();
        bf16x8 af[4], bfr[4];
        #pragma unroll
        for (int i = 0; i < 4; i++)
            af[i] = *(const bf16x8*)&As[wm + i * 16 + lm][quad * 8];
        #pragma unroll
        for (int j = 0; j < 4; j++)
            bfr[j] = *(const bf16x8*)&Bs[wn + j * 16 + lm][quad * 8];
        #pragma unroll
        for (int i = 0; i < 4; i++)
            #pragma unroll
            for (int j = 0; j < 4; j++)
                acc[i][j] = __builtin_amdgcn_mfma_f32_16x16x32_bf16(af[i], bfr[j], acc[i][j], 0, 0, 0);
        __syncthreads();
    }

    // C/D layout: col = lane&15, row = quad*4 + reg  [verified m89/m91]
    #pragma unroll
    for (int i = 0; i < 4; i++) {
        int mbase = m0 + wm + i * 16 + quad * 4;
        #pragma unroll
        for (int j = 0; j < 4; j++) {
            int col = n0 + wn + j * 16 + lm;
            #pragma unroll
            for (int r = 0; r < 4; r++) {
                int m = mbase + r;
                if (m < M) bpk_store(acc[i][j][r], &O[(size_t)m * BPK_D + col]);
            }
        }
    }
}

// ---------------------------------------------------------------------------
// Kernel 4: scores[b,h,t] = (q_h . k[b,t,h,:]) * 128^-0.5. One wave/token.
// ---------------------------------------------------------------------------
__global__ __launch_bounds__(64) void bpk_score_kernel(const bf16* __restrict__ K,
                                                       const float* __restrict__ q,
                                                       float* __restrict__ scores) {
    int tok = blockIdx.x;               // = b*L + t
    int b = tok / BPK_L, t = tok - b * BPK_L;
    int lane = threadIdx.x;
    const bf16* kr = K + (size_t)tok * BPK_D + lane * 16;
    const float* qr = q + lane * 16;
    float s = 0.f;
    #pragma unroll
    for (int i = 0; i < 16; i++)
        s += __bfloat162float(kr[i]) * qr[i];
    s += __shfl_xor(s, 1);
    s += __shfl_xor(s, 2);
    s += __shfl_xor(s, 4);
    if ((lane & 7) == 0) {
        int h = lane >> 3;
        scores[((size_t)b * BPK_H + h) * BPK_L + t] = s * 0.088388347648318447f;
    }
}

// ---------------------------------------------------------------------------
// Kernel 5: per-(b,s) softmax over contiguous segment tokens + weighted V
// pooling. Block 256; each thread does 4 dims (within one head). Empty
// segments -> zeros (matches nan_to_num semantics).
// ---------------------------------------------------------------------------
__global__ __launch_bounds__(256) void bpk_pool_kernel(const float* __restrict__ scores,
                                                       const bf16* __restrict__ V,
                                                       const int* __restrict__ seg_start,
                                                       const int* __restrict__ seg_cnt,
                                                       bf16* __restrict__ pooled) {
    int bs = blockIdx.x;                // = b*S + s
    int b = bs / BPK_S;
    int d0 = threadIdx.x * 4;
    int h = d0 >> 7;
    float a0 = 0.f, a1 = 0.f, a2 = 0.f, a3 = 0.f;
    int cnt = seg_cnt[bs];
    if (cnt > 0) {
        int st = seg_start[bs];
        const float* sc = scores + ((size_t)b * BPK_H + h) * BPK_L + st;
        float m = -1e30f;
        for (int i = 0; i < cnt; i++) m = fmaxf(m, sc[i]);
        float l = 0.f;
        for (int i = 0; i < cnt; i++) l += __expf(sc[i] - m);
        float inv = 1.0f / l;
        const bf16* vp = V + ((size_t)(b * BPK_L + st)) * BPK_D + d0;
        for (int i = 0; i < cnt; i++) {
            float w = __expf(sc[i] - m) * inv;
            uint2 raw = *(const uint2*)(vp + (size_t)i * BPK_D);
            a0 += w * bf_lo(raw.x);
            a1 += w * bf_hi(raw.x);
            a2 += w * bf_lo(raw.y);
            a3 += w * bf_hi(raw.y);
        }
    }
    bf16* pr = pooled + (size_t)bs * BPK_D + d0;
    pr[0] = __float2bfloat16(a0);
    pr[1] = __float2bfloat16(a1);
    pr[2] = __float2bfloat16(a2);
    pr[3] = __float2bfloat16(a3);
}

// ---------------------------------------------------------------------------
extern "C" void kernel_launch(void* const* d_in, const int* in_sizes, int n_in,
                              void* d_out, int out_size, void* d_ws, size_t ws_size,
                              hipStream_t stream) {
    const float* hidden     = (const float*)d_in[0];
    const float* boundaries = (const float*)d_in[1];
    const float* lengths    = (const float*)d_in[2];
    const float* lq         = (const float*)d_in[3];
    const float* Wk         = (const float*)d_in[4];
    const float* Wv         = (const float*)d_in[5];
    const float* Wo         = (const float*)d_in[6];
    const float* gamma      = (const float*)d_in[7];
    const float* beta       = (const float*)d_in[8];
    float* out              = (float*)d_out;

    char* ws = (char*)d_ws;
    size_t off = 0;
    auto carve = [&](size_t bytes) -> char* {
        char* p = ws + off;
        off += (bytes + 255) & ~(size_t)255;
        return p;
    };
    bf16* hn       = (bf16*)carve((size_t)BPK_MPAD * BPK_D * sizeof(bf16));
    bf16* kb       = (bf16*)carve((size_t)BPK_MPAD * BPK_D * sizeof(bf16));
    bf16* vb       = (bf16*)carve((size_t)BPK_MPAD * BPK_D * sizeof(bf16));
    bf16* wkb      = (bf16*)carve((size_t)BPK_D * BPK_D * sizeof(bf16));
    bf16* wvb      = (bf16*)carve((size_t)BPK_D * BPK_D * sizeof(bf16));
    bf16* wob      = (bf16*)carve((size_t)BPK_D * BPK_D * sizeof(bf16));
    float* scores  = (float*)carve((size_t)BPK_B * BPK_H * BPK_L * sizeof(float));
    bf16* pooled   = (bf16*)carve((size_t)BPK_MSPAD * BPK_D * sizeof(bf16));
    int* seg_start = (int*)carve((size_t)BPK_B * BPK_S * sizeof(int));
    int* seg_cnt   = (int*)carve((size_t)BPK_B * BPK_S * sizeof(int));

    const int wgrid = (BPK_D * BPK_D) / (256 * 4);   // 1024 blocks
    bpk_conv_kernel<<<dim3(wgrid), dim3(256), 0, stream>>>(Wk, wkb);
    bpk_conv_kernel<<<dim3(wgrid), dim3(256), 0, stream>>>(Wv, wvb);
    bpk_conv_kernel<<<dim3(wgrid), dim3(256), 0, stream>>>(Wo, wob);
    bpk_seg_kernel<<<dim3(BPK_B), dim3(64), 0, stream>>>(boundaries, lengths, seg_start, seg_cnt);
    bpk_ln_kernel<<<dim3(BPK_M), dim3(256), 0, stream>>>(hidden, gamma, beta, hn);
    bpk_gemm_bt_kernel<bf16><<<dim3(8, BPK_MPAD / 128, 2), dim3(256), 0, stream>>>(hn, wkb, wvb, kb, vb, BPK_M);
    bpk_score_kernel<<<dim3(BPK_M), dim3(64), 0, stream>>>(kb, lq, scores);
    bpk_pool_kernel<<<dim3(BPK_MS), dim3(256), 0, stream>>>(scores, vb, seg_start, seg_cnt, pooled);
    bpk_gemm_bt_kernel<float><<<dim3(8, BPK_MSPAD / 128, 1), dim3(256), 0, stream>>>(pooled, wob, wob, out, out, BPK_MS);
}

// Round 3
// 240.721 us; speedup vs baseline: 2.1400x; 2.1400x over previous
//
#include <hip/hip_runtime.h>
#include <hip/hip_bf16.h>

// Problem constants (BoundaryPredictor2): B=8, L=1500, D=1024, H=8, HD=128, S=300
// All float tensors are float32 (per reference); converted to bf16 internally
// for MFMA GEMMs; output written fp32.
#define BPK_B 8
#define BPK_L 1500
#define BPK_D 1024
#define BPK_H 8
#define BPK_HD 128
#define BPK_S 300
#define BPK_EPS 1e-5f
#define BPK_M (BPK_B * BPK_L)      // 12000 token rows
#define BPK_MPAD 12032             // 94 * 128
#define BPK_MS (BPK_B * BPK_S)     // 2400 pooled rows
#define BPK_MSPAD 2432             // 19 * 128

typedef __hip_bfloat16 bf16;
typedef __bf16 bf16x8 __attribute__((ext_vector_type(8)));
typedef float v4f __attribute__((ext_vector_type(4)));

static __device__ __forceinline__ float bf_lo(unsigned u) {
    return __uint_as_float((u & 0xffffu) << 16);
}
static __device__ __forceinline__ float bf_hi(unsigned u) {
    return __uint_as_float((u >> 16) << 16);
}
static __device__ __forceinline__ void bpk_store(float v, float* p) { *p = v; }
static __device__ __forceinline__ void bpk_store(float v, bf16* p) { *p = __float2bfloat16(v); }

// async global->LDS, 16B per lane, lds dest = wave-uniform base + lane*16
#define BPK_GL2LDS(gsrc, ldst)                                                 \
    __builtin_amdgcn_global_load_lds(                                          \
        (const __attribute__((address_space(1))) void*)(gsrc),                 \
        (__attribute__((address_space(3))) void*)(ldst), 16, 0, 0)

// ---------------------------------------------------------------------------
// Kernel 0: fp32 -> bf16 conversion for the three 1024x1024 weight matrices.
// ---------------------------------------------------------------------------
__global__ __launch_bounds__(256) void bpk_conv3_kernel(
    const float* __restrict__ s0, const float* __restrict__ s1,
    const float* __restrict__ s2, bf16* __restrict__ d0,
    bf16* __restrict__ d1, bf16* __restrict__ d2) {
    const float* s = blockIdx.y == 0 ? s0 : (blockIdx.y == 1 ? s1 : s2);
    bf16* d = blockIdx.y == 0 ? d0 : (blockIdx.y == 1 ? d1 : d2);
    int i = (blockIdx.x * 256 + threadIdx.x) * 4;
    float4 v = *(const float4*)(s + i);
    bf16* p = d + i;
    p[0] = __float2bfloat16(v.x);
    p[1] = __float2bfloat16(v.y);
    p[2] = __float2bfloat16(v.z);
    p[3] = __float2bfloat16(v.w);
}

// ---------------------------------------------------------------------------
// Kernel 1: parallel segment scan. One block per batch. Boundary flags -> LDS,
// block-wide prefix sum (wave shuffle scan + cross-wave LDS combine), token t
// starts segment sid iff (t==0 || flag[t-1]); segment extent = next start,
// clipped to alen. Was: 1 thread x 1500 dependent global RMWs = 278 us.
// ---------------------------------------------------------------------------
__global__ __launch_bounds__(256) void bpk_seg_kernel(
    const float* __restrict__ boundaries, const float* __restrict__ lengths,
    int* __restrict__ seg_start, int* __restrict__ seg_cnt) {
    int b = blockIdx.x;
    int tid = threadIdx.x;
    __shared__ unsigned char flags[1536];
    __shared__ int st_sh[BPK_S + 2];     // starts for sid 0..300 (+pad)
    __shared__ int wsumi[4];
    int alen = (int)(lengths[b] * (float)BPK_L);   // trunc == .astype(int32)
    const float* bd = boundaries + (size_t)b * BPK_L;
    for (int t = tid; t < 1536; t += 256)
        flags[t] = (t < BPK_L && bd[t] >= 0.5f) ? 1 : 0;
    for (int s = tid; s < BPK_S + 2; s += 256) st_sh[s] = BPK_L;
    __syncthreads();
    // per-thread contiguous chunk of 6 tokens (256*6 = 1536 >= 1500)
    int base = tid * 6;
    int lsum = 0;
    #pragma unroll
    for (int j = 0; j < 6; j++) lsum += flags[base + j];
    int lane = tid & 63, wid = tid >> 6;
    int scan = lsum;                      // wave-inclusive scan of chunk sums
    #pragma unroll
    for (int off = 1; off < 64; off <<= 1) {
        int u = __shfl_up(scan, off);
        if (lane >= off) scan += u;
    }
    if (lane == 63) wsumi[wid] = scan;
    __syncthreads();
    int wbase = 0;
    for (int w = 0; w < wid; w++) wbase += wsumi[w];
    int run = wbase + scan - lsum;        // exclusive prefix at chunk start
    #pragma unroll
    for (int j = 0; j < 6; j++) {
        int t = base + j;
        if (t < BPK_L) {
            int sid = run;                // seg_id[t] = #boundaries before t
            if ((t == 0 || flags[t - 1]) && sid <= BPK_S) st_sh[sid] = t;
            if (flags[t]) run++;
        }
    }
    __syncthreads();
    for (int s = tid; s < BPK_S; s += 256) {
        int st = st_sh[s];
        int e = min(st_sh[s + 1], alen);
        int s0 = min(st, alen);
        seg_start[b * BPK_S + s] = st;
        seg_cnt[b * BPK_S + s] = max(0, e - s0);
    }
}

// ---------------------------------------------------------------------------
// Kernel 2: LayerNorm (biased variance), fp32 in -> bf16 out. 1 block/row.
// ---------------------------------------------------------------------------
__global__ __launch_bounds__(256) void bpk_ln_kernel(const float* __restrict__ x,
                                                     const float* __restrict__ gamma,
                                                     const float* __restrict__ beta,
                                                     bf16* __restrict__ y) {
    int row = blockIdx.x;
    int tid = threadIdx.x;
    const float* xr = x + (size_t)row * BPK_D;
    float4 f = *(const float4*)(xr + tid * 4);
    float s = f.x + f.y + f.z + f.w;
    float sq = f.x * f.x + f.y * f.y + f.z * f.z + f.w * f.w;
    #pragma unroll
    for (int off = 32; off > 0; off >>= 1) {
        s += __shfl_down(s, off);
        sq += __shfl_down(sq, off);
    }
    __shared__ float ls[4], lsq[4];
    int wid = tid >> 6, lane = tid & 63;
    if (lane == 0) { ls[wid] = s; lsq[wid] = sq; }
    __syncthreads();
    s = ls[0] + ls[1] + ls[2] + ls[3];
    sq = lsq[0] + lsq[1] + lsq[2] + lsq[3];
    float mu = s * (1.0f / BPK_D);
    float var = sq * (1.0f / BPK_D) - mu * mu;
    float rs = rsqrtf(var + BPK_EPS);
    float4 g = *(const float4*)(gamma + tid * 4);
    float4 bb = *(const float4*)(beta + tid * 4);
    bf16* yr = y + (size_t)row * BPK_D + tid * 4;
    yr[0] = __float2bfloat16((f.x - mu) * rs * g.x + bb.x);
    yr[1] = __float2bfloat16((f.y - mu) * rs * g.y + bb.y);
    yr[2] = __float2bfloat16((f.z - mu) * rs * g.z + bb.z);
    yr[3] = __float2bfloat16((f.w - mu) * rs * g.w + bb.w);
}

// ---------------------------------------------------------------------------
// Kernel 3: GEMM out[m,n] = sum_k A[m,k] * W[n,k]  (A, W both K-major, bf16)
// 128x128 tile, BK=32, 4 waves, each a 64x64 subtile of 4x4 mfma 16x16x32.
// Staging via global_load_lds width=16 (m97 structure): each wave DMAs 4
// 1024B chunks (16 rows each); lane i covers row c*16 + i/4, col (i%4)*8.
// blockIdx.z picks (W0,O0)/(W1,O1). Stores guarded by M.
// ---------------------------------------------------------------------------
template <typename OT>
__global__ __launch_bounds__(256) void bpk_gemm_bt_kernel(
    const bf16* __restrict__ A,
    const bf16* __restrict__ W0, const bf16* __restrict__ W1,
    OT* __restrict__ O0, OT* __restrict__ O1, int M) {
    const bf16* W = blockIdx.z ? W1 : W0;
    OT* O = blockIdx.z ? O1 : O0;
    const int n0 = blockIdx.x * 128;
    const int m0 = blockIdx.y * 128;
    __shared__ bf16 As[128][32];
    __shared__ bf16 Bs[128][32];
    const int tid = threadIdx.x;
    const int lane = tid & 63, wid = tid >> 6;
    const int wm = (wid & 1) * 64, wn = (wid >> 1) * 64;
    const int lm = lane & 15, quad = lane >> 4;

    const int c0 = wid * 2;                       // this wave's chunk pair
    const int rA = c0 * 16 + (lane >> 2);         // source row within tile
    const int colc = (lane & 3) * 8;              // source col (bf16 elems)

    v4f acc[4][4];
    #pragma unroll
    for (int i = 0; i < 4; i++)
        #pragma unroll
        for (int j = 0; j < 4; j++)
            acc[i][j] = (v4f){0.f, 0.f, 0.f, 0.f};

    for (int k0 = 0; k0 < BPK_D; k0 += 32) {
        const bf16* pa = &A[(size_t)(m0 + rA) * BPK_D + k0 + colc];
        const bf16* pw = &W[(size_t)(n0 + rA) * BPK_D + k0 + colc];
        BPK_GL2LDS(pa, &As[c0 * 16][0]);
        BPK_GL2LDS(pa + (size_t)16 * BPK_D, &As[(c0 + 1) * 16][0]);
        BPK_GL2LDS(pw, &Bs[c0 * 16][0]);
        BPK_GL2LDS(pw + (size_t)16 * BPK_D, &Bs[(c0 + 1) * 16][0]);
        __syncthreads();
        bf16x8 af[4], bfr[4];
        #pragma unroll
        for (int i = 0; i < 4; i++)
            af[i] = *(const bf16x8*)&As[wm + i * 16 + lm][quad * 8];
        #pragma unroll
        for (int j = 0; j < 4; j++)
            bfr[j] = *(const bf16x8*)&Bs[wn + j * 16 + lm][quad * 8];
        #pragma unroll
        for (int i = 0; i < 4; i++)
            #pragma unroll
            for (int j = 0; j < 4; j++)
                acc[i][j] = __builtin_amdgcn_mfma_f32_16x16x32_bf16(af[i], bfr[j], acc[i][j], 0, 0, 0);
        __syncthreads();
    }

    // C/D layout: col = lane&15, row = quad*4 + reg  [verified m89/m91]
    #pragma unroll
    for (int i = 0; i < 4; i++) {
        int mbase = m0 + wm + i * 16 + quad * 4;
        #pragma unroll
        for (int j = 0; j < 4; j++) {
            int col = n0 + wn + j * 16 + lm;
            #pragma unroll
            for (int r = 0; r < 4; r++) {
                int m = mbase + r;
                if (m < M) bpk_store(acc[i][j][r], &O[(size_t)m * BPK_D + col]);
            }
        }
    }
}

// ---------------------------------------------------------------------------
// Kernel 4: scores[b,h,t] = (q_h . k[b,t,h,:]) * 128^-0.5. One wave/token.
// ---------------------------------------------------------------------------
__global__ __launch_bounds__(64) void bpk_score_kernel(const bf16* __restrict__ K,
                                                       const float* __restrict__ q,
                                                       float* __restrict__ scores) {
    int tok = blockIdx.x;               // = b*L + t
    int b = tok / BPK_L, t = tok - b * BPK_L;
    int lane = threadIdx.x;
    const bf16* kr = K + (size_t)tok * BPK_D + lane * 16;
    const float* qr = q + lane * 16;
    float s = 0.f;
    #pragma unroll
    for (int i = 0; i < 16; i++)
        s += __bfloat162float(kr[i]) * qr[i];
    s += __shfl_xor(s, 1);
    s += __shfl_xor(s, 2);
    s += __shfl_xor(s, 4);
    if ((lane & 7) == 0) {
        int h = lane >> 3;
        scores[((size_t)b * BPK_H + h) * BPK_L + t] = s * 0.088388347648318447f;
    }
}

// ---------------------------------------------------------------------------
// Kernel 5: per-(b,s) softmax over contiguous segment tokens + weighted V
// pooling. Block 256; each thread does 4 dims (within one head). Empty
// segments -> zeros (matches nan_to_num semantics).
// ---------------------------------------------------------------------------
__global__ __launch_bounds__(256) void bpk_pool_kernel(const float* __restrict__ scores,
                                                       const bf16* __restrict__ V,
                                                       const int* __restrict__ seg_start,
                                                       const int* __restrict__ seg_cnt,
                                                       bf16* __restrict__ pooled) {
    int bs = blockIdx.x;                // = b*S + s
    int b = bs / BPK_S;
    int d0 = threadIdx.x * 4;
    int h = d0 >> 7;
    float a0 = 0.f, a1 = 0.f, a2 = 0.f, a3 = 0.f;
    int cnt = seg_cnt[bs];
    if (cnt > 0) {
        int st = seg_start[bs];
        const float* sc = scores + ((size_t)b * BPK_H + h) * BPK_L + st;
        float m = -1e30f;
        for (int i = 0; i < cnt; i++) m = fmaxf(m, sc[i]);
        float l = 0.f;
        for (int i = 0; i < cnt; i++) l += __expf(sc[i] - m);
        float inv = 1.0f / l;
        const bf16* vp = V + ((size_t)(b * BPK_L + st)) * BPK_D + d0;
        for (int i = 0; i < cnt; i++) {
            float w = __expf(sc[i] - m) * inv;
            uint2 raw = *(const uint2*)(vp + (size_t)i * BPK_D);
            a0 += w * bf_lo(raw.x);
            a1 += w * bf_hi(raw.x);
            a2 += w * bf_lo(raw.y);
            a3 += w * bf_hi(raw.y);
        }
    }
    bf16* pr = pooled + (size_t)bs * BPK_D + d0;
    pr[0] = __float2bfloat16(a0);
    pr[1] = __float2bfloat16(a1);
    pr[2] = __float2bfloat16(a2);
    pr[3] = __float2bfloat16(a3);
}

// ---------------------------------------------------------------------------
extern "C" void kernel_launch(void* const* d_in, const int* in_sizes, int n_in,
                              void* d_out, int out_size, void* d_ws, size_t ws_size,
                              hipStream_t stream) {
    const float* hidden     = (const float*)d_in[0];
    const float* boundaries = (const float*)d_in[1];
    const float* lengths    = (const float*)d_in[2];
    const float* lq         = (const float*)d_in[3];
    const float* Wk         = (const float*)d_in[4];
    const float* Wv         = (const float*)d_in[5];
    const float* Wo         = (const float*)d_in[6];
    const float* gamma      = (const float*)d_in[7];
    const float* beta       = (const float*)d_in[8];
    float* out              = (float*)d_out;

    char* ws = (char*)d_ws;
    size_t off = 0;
    auto carve = [&](size_t bytes) -> char* {
        char* p = ws + off;
        off += (bytes + 255) & ~(size_t)255;
        return p;
    };
    bf16* hn       = (bf16*)carve((size_t)BPK_MPAD * BPK_D * sizeof(bf16));
    bf16* kb       = (bf16*)carve((size_t)BPK_MPAD * BPK_D * sizeof(bf16));
    bf16* vb       = (bf16*)carve((size_t)BPK_MPAD * BPK_D * sizeof(bf16));
    bf16* wkb      = (bf16*)carve((size_t)BPK_D * BPK_D * sizeof(bf16));
    bf16* wvb      = (bf16*)carve((size_t)BPK_D * BPK_D * sizeof(bf16));
    bf16* wob      = (bf16*)carve((size_t)BPK_D * BPK_D * sizeof(bf16));
    float* scores  = (float*)carve((size_t)BPK_B * BPK_H * BPK_L * sizeof(float));
    bf16* pooled   = (bf16*)carve((size_t)BPK_MSPAD * BPK_D * sizeof(bf16));
    int* seg_start = (int*)carve((size_t)BPK_B * BPK_S * sizeof(int));
    int* seg_cnt   = (int*)carve((size_t)BPK_B * BPK_S * sizeof(int));

    const int wgrid = (BPK_D * BPK_D) / (256 * 4);   // 1024 blocks per matrix
    bpk_conv3_kernel<<<dim3(wgrid, 3), dim3(256), 0, stream>>>(Wk, Wv, Wo, wkb, wvb, wob);
    bpk_seg_kernel<<<dim3(BPK_B), dim3(256), 0, stream>>>(boundaries, lengths, seg_start, seg_cnt);
    bpk_ln_kernel<<<dim3(BPK_M), dim3(256), 0, stream>>>(hidden, gamma, beta, hn);
    bpk_gemm_bt_kernel<bf16><<<dim3(8, BPK_MPAD / 128, 2), dim3(256), 0, stream>>>(hn, wkb, wvb, kb, vb, BPK_M);
    bpk_score_kernel<<<dim3(BPK_M), dim3(64), 0, stream>>>(kb, lq, scores);
    bpk_pool_kernel<<<dim3(BPK_MS), dim3(256), 0, stream>>>(scores, vb, seg_start, seg_cnt, pooled);
    bpk_gemm_bt_kernel<float><<<dim3(8, BPK_MSPAD / 128, 1), dim3(256), 0, stream>>>(pooled, wob, wob, out, out, BPK_MS);
}